// Round 8
// baseline (201.973 us; speedup 1.0000x reference)
//
#include <hip/hip_runtime.h>
#include <hip/hip_bf16.h>
#include <cstdint>

#define B_SIZE 4096
#define TWO_B  8192
#define DIM    512           // row length; fp8 => 512 bytes per row
#define NBLK   1056          // blocks: (I,J), I in [0,32), J in [2I,64)
// exp(x/t) = exp2(x * log2(e)/t), t = 0.5
#define EXP_SCALE 2.8853900817779268f
#define SCALE1 0x7F7F7F7F    // e8m0 scale = 2^0 = 1.0 in every byte

typedef __attribute__((ext_vector_type(4)))  float f32x4;
typedef __attribute__((ext_vector_type(16))) float f32x16;
typedef __attribute__((ext_vector_type(4)))  int   i32x4;
typedef __attribute__((ext_vector_type(8)))  int   i32x8;

// raw waitcnt: vmcnt(n) with lgkmcnt/expcnt unconstrained (gfx9 encoding)
#define WAITVM(n) __builtin_amdgcn_s_waitcnt(0xF70 | (n))
#define BARRIER() __builtin_amdgcn_s_barrier()

// ---------- helpers ----------
__device__ __forceinline__ void async16(const void* g, void* l) {
    __builtin_amdgcn_global_load_lds(
        (const __attribute__((address_space(1))) unsigned int*)g,
        (__attribute__((address_space(3))) unsigned int*)l,
        16, 0, 0);
}

// ---------- kernel 1: L2-normalize rows -> fp8 reps, fp32 positives ----------
__global__ __launch_bounds__(256) void norm_pos_kernel(
    const float* __restrict__ emb_i, const float* __restrict__ emb_j,
    unsigned char* __restrict__ reps, float* __restrict__ pos,
    float* __restrict__ out)
{
    __shared__ float sc[3][4];
    int b = blockIdx.x, t = threadIdx.x;
    if (b == 0 && t == 0) out[0] = 0.0f;       // loss kernel accumulates atomically

    const float2* ri = (const float2*)(emb_i + (size_t)b * DIM);
    const float2* rj = (const float2*)(emb_j + (size_t)b * DIM);
    float2 xi = ri[t], xj = rj[t];
    float si = xi.x * xi.x + xi.y * xi.y;
    float sj = xj.x * xj.x + xj.y * xj.y;
    #pragma unroll
    for (int o = 32; o > 0; o >>= 1) { si += __shfl_down(si, o, 64); sj += __shfl_down(sj, o, 64); }
    int lane = t & 63, w = t >> 6;
    if (lane == 0) { sc[0][w] = si; sc[1][w] = sj; }
    __syncthreads();
    float ni2 = sc[0][0] + sc[0][1] + sc[0][2] + sc[0][3];
    float nj2 = sc[1][0] + sc[1][1] + sc[1][2] + sc[1][3];
    float rni = 1.0f / fmaxf(sqrtf(ni2), 1e-12f);
    float rnj = 1.0f / fmaxf(sqrtf(nj2), 1e-12f);
    float zix = xi.x * rni, ziy = xi.y * rni;
    float zjx = xj.x * rnj, zjy = xj.y * rnj;
    // pack 2 floats -> 2 OCP e4m3 bytes (HW cvt, gfx950)
    int pki = __builtin_amdgcn_cvt_pk_fp8_f32(zix, ziy, 0, false);
    int pkj = __builtin_amdgcn_cvt_pk_fp8_f32(zjx, zjy, 0, false);
    ((unsigned short*)(reps + (size_t)b * DIM))[t]            = (unsigned short)pki;
    ((unsigned short*)(reps + (size_t)(b + B_SIZE) * DIM))[t] = (unsigned short)pkj;
    float d = zix * zjx + ziy * zjy;
    #pragma unroll
    for (int o = 32; o > 0; o >>= 1) d += __shfl_down(d, o, 64);
    if (lane == 0) sc[2][w] = d;
    __syncthreads();
    if (t == 0) pos[b] = sc[2][0] + sc[2][1] + sc[2][2] + sc[2][3];
}

// ---------- kernel 2: symmetric fused R*R^T (MX-scaled fp8 MFMA) + masked exp sums ----------
// ROUND 8: round-1's correctness-VERIFIED MX core (mfma_scale_f32_32x32x64_f8f6f4, unit
// e8m0 scales -> 2x non-scaled fp8 rate) transplanted into round-6's occupancy-VERIFIED
// skeleton (256x128 tile, 8 waves of 64x64, launch_bounds(512,4) -> <=128 regs/wave ->
// 2 blocks/CU). Per wave per K-tile: 4 scaled MFMAs + 8 ds_read_b128 (conflict-free:
// 8 start-bank groups x 4-bank spans tile the 32 banks at the 8-beat minimum).
// Wave acc: 2x2 f32x16 = 64 AGPR; frags 4x i32x8 = 32 VGPR.
// fp8 LDS tiles: row r = 4 pieces of 16 B, piece p stored at p ^ ((r^(r>>2))&3).
// 2-buffer / 2-barrier pipeline (verified), counted vmcnt(3), 2 tiles in flight.
// A/B frag (verified r1): row = lane&31 (+32 for second frag), K = (lane>>5)*32 + [0,32).
// C/D (verified r1): col = lane&31, row = (reg&3) + 8*(reg>>2) + 4*(lane>>5).
// Epilogue: atomic-free part[64][8192]; slot part[x][y in tile g]: g<=x row-side of
// (g>>1,x); g>x col-side of (x>>1,g). Each written exactly once.
#define BK 64
#define KITERS 8             // DIM / BK

__global__ __launch_bounds__(512, 4) void sim_denom_kernel(
    const unsigned char* __restrict__ reps,
    const int* __restrict__ target,
    float* __restrict__ part)
{
    __shared__ __align__(16) unsigned char As0[256 * BK];
    __shared__ __align__(16) unsigned char As1[256 * BK];
    __shared__ __align__(16) unsigned char Bs0[128 * BK];
    __shared__ __align__(16) unsigned char Bs1[128 * BK];

    int t = threadIdx.x;
    // XCD-chunked remap: contiguous 132-run per XCD (1056 = 8*132, bijective).
    int id0 = blockIdx.x;
    int id = (id0 & 7) * 132 + (id0 >> 3);

    // --- band decode: 8x16 (I,J) supertile bands over the J>=2I region ---
    const int bA[10]   = {0,0,0,0,1,1,1,2,2,3};
    const int bB[10]   = {0,1,2,3,1,2,3,2,3,3};
    const int boff[11] = {0,72,200,328,456,528,656,784,856,984,1056};
    int s = 0;
    while (boff[s + 1] <= id) s++;
    int l = id - boff[s];
    int I, J;
    if (bA[s] == bB[s]) {                 // triangular band: start(r) = r*(17-r)
        int r = 0;
        while ((r + 1) * (16 - r) <= l) r++;
        I = bA[s] * 8 + r;
        J = bB[s] * 16 + 2 * r + (l - r * (17 - r));
    } else { I = bA[s] * 8 + (l >> 4); J = bB[s] * 16 + (l & 15); }

    int brow = I * 256;
    int bcol = J * 128;

    int wave = t >> 6, lane = t & 63;
    int wr = wave >> 1, wc = wave & 1;       // 4x2 waves, each 64x64 output
    int kh = lane >> 5, l31 = lane & 31;     // K-half, row/col-in-subtile

    f32x16 acc[2][2];
    acc[0][0] = (f32x16)0.0f; acc[0][1] = (f32x16)0.0f;
    acc[1][0] = (f32x16)0.0f; acc[1][1] = (f32x16)0.0f;

    // staging: A: 2 calls, call c -> row c*128 + (t>>2), LDS byte t*16 + c*8192;
    // B: 1 call, row t>>2. swizzled source piece = (t&3) ^ ((row ^ (row>>2)) & 3)
    int srow = t >> 2;
    int sp   = (t & 3) ^ ((srow ^ (srow >> 2)) & 3);
    const unsigned char* gA = reps + (size_t)(brow + srow) * DIM + sp * 16;
    const unsigned char* gB = reps + (size_t)(bcol + srow) * DIM + sp * 16;

    auto stage = [&](unsigned char* Ab, unsigned char* Bb, int k0) {
        async16(gA + k0, Ab + t * 16);
        async16(gA + k0 + 128 * DIM, Ab + t * 16 + 8192);
        async16(gB + k0, Bb + t * 16);
    };

    // fragment rows + loop-invariant swizzled LDS byte offsets
    // (row+32 preserves (r&3) and ((r>>2)&3) -> shared swz)
    int ra0 = wr * 64 + l31;                 // 0..255
    int rb0 = wc * 64 + l31;                 // 0..127
    int swa = (ra0 ^ (ra0 >> 2)) & 3;
    int swb = (rb0 ^ (rb0 >> 2)) & 3;
    int p0  = kh * 2;                        // this lane's K-half = pieces {p0, p0+1}
    int oa0l = ra0 * 64 + ((p0 ^ swa) * 16);
    int oa0h = ra0 * 64 + (((p0 + 1) ^ swa) * 16);
    int oa1l = oa0l + 32 * 64, oa1h = oa0h + 32 * 64;
    int ob0l = rb0 * 64 + ((p0 ^ swb) * 16);
    int ob0h = rb0 * 64 + (((p0 + 1) ^ swb) * 16);
    int ob1l = ob0l + 32 * 64, ob1h = ob0h + 32 * 64;

    auto ldf = [&](const unsigned char* base, int ol, int oh) -> i32x8 {
        i32x4 lo = *(const i32x4*)(base + ol);
        i32x4 hi = *(const i32x4*)(base + oh);
        i32x8 r;
        r[0] = lo[0]; r[1] = lo[1]; r[2] = lo[2]; r[3] = lo[3];
        r[4] = hi[0]; r[5] = hi[1]; r[6] = hi[2]; r[7] = hi[3];
        return r;
    };

    auto compute = [&](const unsigned char* Ab, const unsigned char* Bb) {
        i32x8 a0 = ldf(Ab, oa0l, oa0h);
        i32x8 a1 = ldf(Ab, oa1l, oa1h);
        i32x8 b0 = ldf(Bb, ob0l, ob0h);
        i32x8 b1 = ldf(Bb, ob1l, ob1h);
        acc[0][0] = __builtin_amdgcn_mfma_scale_f32_32x32x64_f8f6f4(
            a0, b0, acc[0][0], 0, 0, 0, SCALE1, 0, SCALE1);
        acc[0][1] = __builtin_amdgcn_mfma_scale_f32_32x32x64_f8f6f4(
            a0, b1, acc[0][1], 0, 0, 0, SCALE1, 0, SCALE1);
        acc[1][0] = __builtin_amdgcn_mfma_scale_f32_32x32x64_f8f6f4(
            a1, b0, acc[1][0], 0, 0, 0, SCALE1, 0, SCALE1);
        acc[1][1] = __builtin_amdgcn_mfma_scale_f32_32x32x64_f8f6f4(
            a1, b1, acc[1][1], 0, 0, 0, SCALE1, 0, SCALE1);
    };

    // prologue: two tiles in flight (6 DMAs outstanding per thread)
    stage(As0, Bs0, 0);
    stage(As1, Bs1, BK);

    #pragma unroll
    for (int k = 0; k < KITERS; k++) {
        unsigned char* Ac = (k & 1) ? As1 : As0;
        unsigned char* Bc = (k & 1) ? Bs1 : Bs0;
        if (k < KITERS - 1) WAITVM(3); else WAITVM(0);   // drain loads(k), keep loads(k+1) in flight
        BARRIER();                         // all waves' loads(k) landed
        compute(Ac, Bc);
        BARRIER();                         // all waves done reading buf(k)
        if (k + 2 < KITERS) stage(Ac, Bc, (k + 2) * BK);
    }

    // ---------- epilogue: masked exp + row/col sums, atomic-free ----------
    // 32x32 C/D: col=lane&31, row=(reg&3)+8*(reg>>2)+4*kh. Wave rows in 128-half h=wr>>1.
    // Positives: global col-row = 4096 <=> (J - rtile)==32 at ((rl&127)==cl).
    // LDS reuse: As0/Bs0 (last compute read k==6, fenced by k==7's barriers).
    int h = wr >> 1;
    int rtile = 2 * I + h;
    bool haspos = (J - rtile == 32);
    int cl0 = wc * 64 + l31, cl1 = cl0 + 32;
    int labc0 = target[(bcol + cl0) & (B_SIZE - 1)];
    int labc1 = target[(bcol + cl1) & (B_SIZE - 1)];

    float* red_row = (float*)As0;    // [2][256] = 2 KB
    float* red_col = (float*)Bs0;    // [2][2][128] = 2 KB

    float colacc0 = 0.0f, colacc1 = 0.0f;
    #pragma unroll
    for (int mi = 0; mi < 2; mi++) {
        #pragma unroll
        for (int g = 0; g < 4; g++) {
            #pragma unroll
            for (int j = 0; j < 4; j++) {
                int reg = g * 4 + j;
                int rl = wr * 64 + mi * 32 + g * 8 + kh * 4 + j;   // 0..255
                int labr = target[(brow + rl) & (B_SIZE - 1)];
                bool pp0 = haspos && ((rl & 127) == cl0);
                bool pp1 = haspos && ((rl & 127) == cl1);
                float e0 = ((labr == labc0) && !pp0)
                               ? 0.0f
                               : __builtin_amdgcn_exp2f(acc[mi][0][reg] * EXP_SCALE);
                float e1 = ((labr == labc1) && !pp1)
                               ? 0.0f
                               : __builtin_amdgcn_exp2f(acc[mi][1][reg] * EXP_SCALE);
                colacc0 += e0; colacc1 += e1;
                float racc = e0 + e1;
                racc += __shfl_xor(racc, 1, 64);
                racc += __shfl_xor(racc, 2, 64);
                racc += __shfl_xor(racc, 4, 64);
                racc += __shfl_xor(racc, 8, 64);
                racc += __shfl_xor(racc, 16, 64);
                if (l31 == 0) red_row[wc * 256 + rl] = racc;   // lanes 0 (kh=0) & 32 (kh=1): distinct rl
            }
        }
    }
    colacc0 += __shfl_xor(colacc0, 32, 64);
    colacc1 += __shfl_xor(colacc1, 32, 64);
    if (lane < 32) {
        red_col[h * 256 + (wr & 1) * 128 + wc * 64 + l31]      = colacc0;
        red_col[h * 256 + (wr & 1) * 128 + wc * 64 + 32 + l31] = colacc1;
    }
    BARRIER();
    if (t < 256) {
        int th = t >> 7;                       // row-half of this output row
        if (2 * I + th <= J) {                 // suppress even-diag duplicate lower half
            float rs = red_row[t] + red_row[256 + t];
            part[(size_t)J * TWO_B + brow + t] = rs;
        }
    } else if (t < 512) {
        int c = t - 256;
        int ch = c >> 7, cc = c & 127;         // which row-half's col-sums
        int rt = 2 * I + ch;
        if (rt < J) {                          // skip diag (row-side covers) + duplicate half
            float cs = red_col[ch * 256 + cc] + red_col[ch * 256 + 128 + cc];
            part[(size_t)rt * TWO_B + bcol + cc] = cs;
        }
    }
}

// ---------- kernel 3: final loss (sum 64 part slices, then log/pos reduce) ----------
__global__ __launch_bounds__(256) void loss_kernel(
    const float* __restrict__ part, const float* __restrict__ pos,
    float* __restrict__ out)
{
    __shared__ float sc[4];
    int t = threadIdx.x, b = blockIdx.x;
    int i = b * 256 + t;
    float s = 0.0f;
    #pragma unroll
    for (int x = 0; x < 64; x++) s += part[(size_t)x * TWO_B + i];
    float v = logf(s + 1e-7f);                         // 32 blocks x 256 = 8192
    float p = (i < B_SIZE) ? pos[i] : 0.0f;
    // loss = (sum log(denom) - (2/t) * sum pos) / 2B ; 2/t = 4
    float v2 = v - 4.0f * p;
    #pragma unroll
    for (int o = 32; o > 0; o >>= 1) v2 += __shfl_down(v2, o, 64);
    int lane = t & 63, w = t >> 6;
    if (lane == 0) sc[w] = v2;
    __syncthreads();
    if (t == 0) atomicAdd(out, (sc[0] + sc[1] + sc[2] + sc[3]) * (1.0f / (float)TWO_B));
}

// ---------- launcher ----------
extern "C" void kernel_launch(void* const* d_in, const int* in_sizes, int n_in,
                              void* d_out, int out_size, void* d_ws, size_t ws_size,
                              hipStream_t stream)
{
    const float* emb_i  = (const float*)d_in[0];
    const float* emb_j  = (const float*)d_in[1];
    const int*   target = (const int*)d_in[2];
    float* out = (float*)d_out;

    char* ws = (char*)d_ws;
    unsigned char* reps = (unsigned char*)ws;                        // 8192*512 = 4 MB (fp8)
    float* pos   = (float*)(ws + (size_t)TWO_B * DIM);               // 16 KB
    float* part  = (float*)(ws + (size_t)TWO_B * DIM + B_SIZE * 4);  // 64*8192*4 = 2 MB

    norm_pos_kernel<<<B_SIZE, 256, 0, stream>>>(emb_i, emb_j, reps, pos, out);
    sim_denom_kernel<<<NBLK, 512, 0, stream>>>(reps, target, part);
    loss_kernel<<<TWO_B / 256, 256, 0, stream>>>(part, pos, out);
}

// Round 9
// 108.749 us; speedup vs baseline: 1.8572x; 1.8572x over previous
//
#include <hip/hip_runtime.h>
#include <hip/hip_bf16.h>
#include <cstdint>

#define B_SIZE 4096
#define TWO_B  8192
#define DIM    512           // row length; fp8 => 512 bytes per row
#define NBLK   1056          // blocks: (I,J), I in [0,32), J in [2I,64)
// exp(x/t) = exp2(x * log2(e)/t), t = 0.5
#define EXP_SCALE 2.8853900817779268f

typedef __attribute__((ext_vector_type(4))) float f32x4;

// raw waitcnt: vmcnt(n) with lgkmcnt/expcnt unconstrained (gfx9 encoding)
#define WAITVM(n) __builtin_amdgcn_s_waitcnt(0xF70 | (n))
#define BARRIER() __builtin_amdgcn_s_barrier()

// ---------- helpers ----------
__device__ __forceinline__ void async16(const void* g, void* l) {
    __builtin_amdgcn_global_load_lds(
        (const __attribute__((address_space(1))) unsigned int*)g,
        (__attribute__((address_space(3))) unsigned int*)l,
        16, 0, 0);
}

// ---------- kernel 1: L2-normalize rows -> fp8 reps, fp32 positives ----------
__global__ __launch_bounds__(256) void norm_pos_kernel(
    const float* __restrict__ emb_i, const float* __restrict__ emb_j,
    unsigned char* __restrict__ reps, float* __restrict__ pos,
    float* __restrict__ out)
{
    __shared__ float sc[3][4];
    int b = blockIdx.x, t = threadIdx.x;
    if (b == 0 && t == 0) out[0] = 0.0f;       // loss kernel accumulates atomically

    const float2* ri = (const float2*)(emb_i + (size_t)b * DIM);
    const float2* rj = (const float2*)(emb_j + (size_t)b * DIM);
    float2 xi = ri[t], xj = rj[t];
    float si = xi.x * xi.x + xi.y * xi.y;
    float sj = xj.x * xj.x + xj.y * xj.y;
    #pragma unroll
    for (int o = 32; o > 0; o >>= 1) { si += __shfl_down(si, o, 64); sj += __shfl_down(sj, o, 64); }
    int lane = t & 63, w = t >> 6;
    if (lane == 0) { sc[0][w] = si; sc[1][w] = sj; }
    __syncthreads();
    float ni2 = sc[0][0] + sc[0][1] + sc[0][2] + sc[0][3];
    float nj2 = sc[1][0] + sc[1][1] + sc[1][2] + sc[1][3];
    float rni = 1.0f / fmaxf(sqrtf(ni2), 1e-12f);
    float rnj = 1.0f / fmaxf(sqrtf(nj2), 1e-12f);
    float zix = xi.x * rni, ziy = xi.y * rni;
    float zjx = xj.x * rnj, zjy = xj.y * rnj;
    // pack 2 floats -> 2 OCP e4m3 bytes (HW cvt, gfx950)
    int pki = __builtin_amdgcn_cvt_pk_fp8_f32(zix, ziy, 0, false);
    int pkj = __builtin_amdgcn_cvt_pk_fp8_f32(zjx, zjy, 0, false);
    ((unsigned short*)(reps + (size_t)b * DIM))[t]            = (unsigned short)pki;
    ((unsigned short*)(reps + (size_t)(b + B_SIZE) * DIM))[t] = (unsigned short)pkj;
    float d = zix * zjx + ziy * zjy;
    #pragma unroll
    for (int o = 32; o > 0; o >>= 1) d += __shfl_down(d, o, 64);
    if (lane == 0) sc[2][w] = d;
    __syncthreads();
    if (t == 0) pos[b] = sc[2][0] + sc[2][1] + sc[2][2] + sc[2][3];
}

// ---------- kernel 2: symmetric fused R*R^T (fp8 MFMA) + masked exp row/col sums ----------
// 256x128 tile, 8 waves (4 row-strips x 2 col-strips), each wave 64x64 (acc[4][4], 64 AGPR).
// __launch_bounds__(512, 4): <=128 unified regs/wave -> 2 blocks/CU (verified r6: occ 29.7%).
// K-loop: verified r6 2-buffer / 2-barrier pipeline, counted vmcnt(3), 2 tiles in flight.
// ROUND 9: epilogue restructure. The 4-deep shfl_xor chain per output row (64 serial
// DS-pipe shuffles/wave, ~600+ unhidable cycles) is replaced by: each lane writes its
// 4-col partial to LDS red[wc][row][lm] (ONE ds_write_b32 per row, stride 20 words ->
// 2-way bank alias only), then a 256-thread pass sums 16+16 lm-partials per row via
// 8x ds_read_b128 (row base 80 B = 16-aligned). LDS repurposed from staging buffers
// (unified SMEM block; all staging reads fenced by k==7's end barrier).
// fp8 LDS tiles: row r = 4 pieces of 16 B, piece p stored at p ^ ((r^(r>>2))&3).
// Epilogue coverage: atomic-free part[64][8192]; slot part[x][y in tile g]: g<=x row-side
// of (g>>1,x); g>x col-side of (x>>1,g). Each written exactly once.
#define BK 64
#define KITERS 8             // DIM / BK
#define RSTR 20              // red row stride in words (80 B: 16-aligned, bank-spread)

__global__ __launch_bounds__(512, 4) void sim_denom_kernel(
    const unsigned char* __restrict__ reps,
    const int* __restrict__ target,
    float* __restrict__ part)
{
    // unified LDS: staging layout [As0 16K | As1 16K | Bs0 8K | Bs1 8K] = 48 KB;
    // epilogue overlay [red0 20K | red1 20K | red_col 2K] = 42 KB (fenced by k=7 barrier)
    __shared__ __align__(16) unsigned char SMEM[49152];
    unsigned char* As0 = SMEM;
    unsigned char* As1 = SMEM + 16384;
    unsigned char* Bs0 = SMEM + 32768;
    unsigned char* Bs1 = SMEM + 40960;

    int t = threadIdx.x;
    // XCD-chunked remap: contiguous 132-run per XCD (1056 = 8*132, bijective).
    int id0 = blockIdx.x;
    int id = (id0 & 7) * 132 + (id0 >> 3);

    // --- band decode: 8x16 (I,J) supertile bands over the J>=2I region ---
    const int bA[10]   = {0,0,0,0,1,1,1,2,2,3};
    const int bB[10]   = {0,1,2,3,1,2,3,2,3,3};
    const int boff[11] = {0,72,200,328,456,528,656,784,856,984,1056};
    int s = 0;
    while (boff[s + 1] <= id) s++;
    int l = id - boff[s];
    int I, J;
    if (bA[s] == bB[s]) {                 // triangular band: start(r) = r*(17-r)
        int r = 0;
        while ((r + 1) * (16 - r) <= l) r++;
        I = bA[s] * 8 + r;
        J = bB[s] * 16 + 2 * r + (l - r * (17 - r));
    } else { I = bA[s] * 8 + (l >> 4); J = bB[s] * 16 + (l & 15); }

    int brow = I * 256;
    int bcol = J * 128;

    int wave = t >> 6, lane = t & 63;
    int wr = wave >> 1, wc = wave & 1;       // 4x2 waves, each 64x64 output
    int quad = lane >> 4, lm = lane & 15;

    f32x4 acc[4][4];
    #pragma unroll
    for (int i = 0; i < 4; i++)
        #pragma unroll
        for (int j = 0; j < 4; j++) acc[i][j] = (f32x4)0.0f;

    // staging: A: 2 calls, call c -> row c*128 + (t>>2), LDS byte t*16 + c*8192;
    // B: 1 call, row t>>2. swizzled source piece = (t&3) ^ ((row ^ (row>>2)) & 3)
    int srow = t >> 2;
    int sp   = (t & 3) ^ ((srow ^ (srow >> 2)) & 3);
    const unsigned char* gA = reps + (size_t)(brow + srow) * DIM + sp * 16;
    const unsigned char* gB = reps + (size_t)(bcol + srow) * DIM + sp * 16;

    auto stage = [&](unsigned char* Ab, unsigned char* Bb, int k0) {
        async16(gA + k0, Ab + t * 16);
        async16(gA + k0 + 128 * DIM, Ab + t * 16 + 8192);
        async16(gB + k0, Bb + t * 16);
    };
    auto compute = [&](const unsigned char* Ab, const unsigned char* Bb) {
        #pragma unroll
        for (int ss = 0; ss < 2; ss++) {       // two K=32 sub-steps of BK=64
            long af[4], bf[4];
            #pragma unroll
            for (int mi = 0; mi < 4; mi++) {
                int rl = wr * 64 + mi * 16 + lm;           // 0..255
                int p = (ss * 2 + (quad >> 1)) ^ ((rl ^ (rl >> 2)) & 3);
                af[mi] = *(const long*)(Ab + rl * 64 + p * 16 + (quad & 1) * 8);
            }
            #pragma unroll
            for (int ni = 0; ni < 4; ni++) {
                int cl = wc * 64 + ni * 16 + lm;           // 0..127
                int p = (ss * 2 + (quad >> 1)) ^ ((cl ^ (cl >> 2)) & 3);
                bf[ni] = *(const long*)(Bb + cl * 64 + p * 16 + (quad & 1) * 8);
            }
            #pragma unroll
            for (int mi = 0; mi < 4; mi++)
                #pragma unroll
                for (int ni = 0; ni < 4; ni++)
                    acc[mi][ni] = __builtin_amdgcn_mfma_f32_16x16x32_fp8_fp8(
                        af[mi], bf[ni], acc[mi][ni], 0, 0, 0);
        }
    };

    // prologue: two tiles in flight (6 DMAs outstanding per thread)
    stage(As0, Bs0, 0);
    stage(As1, Bs1, BK);

    #pragma unroll
    for (int k = 0; k < KITERS; k++) {
        unsigned char* Ac = (k & 1) ? As1 : As0;
        unsigned char* Bc = (k & 1) ? Bs1 : Bs0;
        if (k < KITERS - 1) WAITVM(3); else WAITVM(0);   // drain loads(k), keep loads(k+1) in flight
        BARRIER();                         // all waves' loads(k) landed
        compute(Ac, Bc);
        BARRIER();                         // all waves done reading buf(k)
        if (k + 2 < KITERS) stage(Ac, Bc, (k + 2) * BK);
    }

    // ---------- epilogue: masked exp + row/col sums, atomic-free, shfl-free rows ----------
    // C/D layout: col=lane&15, row=quad*4+reg. Wave's rows all in one 128-half h.
    // Positives: global col-row = 4096 <=> (J - rtile)==32 at ((rl&127)==cl).
    int h = wr >> 1;
    int rtile = 2 * I + h;
    bool haspos = (J - rtile == 32);
    int labc[4];
    #pragma unroll
    for (int ni = 0; ni < 4; ni++)
        labc[ni] = target[(bcol + wc * 64 + ni * 16 + lm) & (B_SIZE - 1)];

    float* red0    = (float*)SMEM;               // [256][RSTR] lm-partials, wc=0
    float* red1    = (float*)(SMEM + 20480);     // [256][RSTR] lm-partials, wc=1
    float* red_col = (float*)(SMEM + 40960);     // [2][2][128] col partials
    float* redw    = wc ? red1 : red0;

    float colacc[4] = {0.f, 0.f, 0.f, 0.f};
    #pragma unroll
    for (int mi = 0; mi < 4; mi++) {
        #pragma unroll
        for (int r = 0; r < 4; r++) {
            int rl = wr * 64 + mi * 16 + quad * 4 + r;     // 0..255
            int labr = target[(brow + rl) & (B_SIZE - 1)];
            float rowacc = 0.0f;
            #pragma unroll
            for (int ni = 0; ni < 4; ni++) {
                int cl = wc * 64 + ni * 16 + lm;
                bool pospair = haspos && ((rl & 127) == cl);
                bool masked = (labr == labc[ni]) && !pospair;
                float e = masked ? 0.0f
                                 : __builtin_amdgcn_exp2f(acc[mi][ni][r] * EXP_SCALE);
                rowacc += e;
                colacc[ni] += e;
            }
            redw[rl * RSTR + lm] = rowacc;       // all 64 lanes, distinct (rl,lm) slots
        }
    }
    #pragma unroll
    for (int ni = 0; ni < 4; ni++) {
        float c = colacc[ni];
        c += __shfl_xor(c, 16, 64);
        c += __shfl_xor(c, 32, 64);
        if (quad == 0) red_col[h * 256 + (wr & 1) * 128 + wc * 64 + ni * 16 + lm] = c;
    }
    BARRIER();
    if (t < 256) {
        int th = t >> 7;                       // row-half of this output row
        if (2 * I + th <= J) {                 // suppress even-diag duplicate lower half
            const f32x4* r0 = (const f32x4*)(red0 + t * RSTR);
            const f32x4* r1 = (const f32x4*)(red1 + t * RSTR);
            f32x4 v = r0[0] + r0[1] + r0[2] + r0[3]
                    + r1[0] + r1[1] + r1[2] + r1[3];
            part[(size_t)J * TWO_B + brow + t] = v[0] + v[1] + v[2] + v[3];
        }
    } else if (t < 512) {
        int c = t - 256;
        int ch = c >> 7, cc = c & 127;         // which row-half's col-sums
        int rt = 2 * I + ch;
        if (rt < J) {                          // skip diag (row-side covers) + duplicate half
            float cs = red_col[ch * 256 + cc] + red_col[ch * 256 + 128 + cc];
            part[(size_t)rt * TWO_B + bcol + cc] = cs;
        }
    }
}

// ---------- kernel 3: final loss (sum 64 part slices, then log/pos reduce) ----------
__global__ __launch_bounds__(256) void loss_kernel(
    const float* __restrict__ part, const float* __restrict__ pos,
    float* __restrict__ out)
{
    __shared__ float sc[4];
    int t = threadIdx.x, b = blockIdx.x;
    int i = b * 256 + t;
    float s = 0.0f;
    #pragma unroll
    for (int x = 0; x < 64; x++) s += part[(size_t)x * TWO_B + i];
    float v = logf(s + 1e-7f);                         // 32 blocks x 256 = 8192
    float p = (i < B_SIZE) ? pos[i] : 0.0f;
    // loss = (sum log(denom) - (2/t) * sum pos) / 2B ; 2/t = 4
    float v2 = v - 4.0f * p;
    #pragma unroll
    for (int o = 32; o > 0; o >>= 1) v2 += __shfl_down(v2, o, 64);
    int lane = t & 63, w = t >> 6;
    if (lane == 0) sc[w] = v2;
    __syncthreads();
    if (t == 0) atomicAdd(out, (sc[0] + sc[1] + sc[2] + sc[3]) * (1.0f / (float)TWO_B));
}

// ---------- launcher ----------
extern "C" void kernel_launch(void* const* d_in, const int* in_sizes, int n_in,
                              void* d_out, int out_size, void* d_ws, size_t ws_size,
                              hipStream_t stream)
{
    const float* emb_i  = (const float*)d_in[0];
    const float* emb_j  = (const float*)d_in[1];
    const int*   target = (const int*)d_in[2];
    float* out = (float*)d_out;

    char* ws = (char*)d_ws;
    unsigned char* reps = (unsigned char*)ws;                        // 8192*512 = 4 MB (fp8)
    float* pos   = (float*)(ws + (size_t)TWO_B * DIM);               // 16 KB
    float* part  = (float*)(ws + (size_t)TWO_B * DIM + B_SIZE * 4);  // 64*8192*4 = 2 MB

    norm_pos_kernel<<<B_SIZE, 256, 0, stream>>>(emb_i, emb_j, reps, pos, out);
    sim_denom_kernel<<<NBLK, 512, 0, stream>>>(reps, target, part);
    loss_kernel<<<TWO_B / 256, 256, 0, stream>>>(part, pos, out);
}

// Round 10
// 106.497 us; speedup vs baseline: 1.8965x; 1.0211x over previous
//
#include <hip/hip_runtime.h>
#include <hip/hip_bf16.h>
#include <cstdint>

#define B_SIZE 4096
#define TWO_B  8192
#define DIM    512           // row length; i8 => 512 bytes per row
#define NBLK   1056          // blocks: (I,J), I in [0,32), J in [2I,64)
// exp(sim/t) with sim = acc/127^2, t=0.5: exp2(acc * log2(e)/(t*16129))
#define IEXP_SCALE 1.7889578968877387e-4f
#define EXP_SCALE  2.8853900817779268f

typedef __attribute__((ext_vector_type(4))) float f32x4;
typedef __attribute__((ext_vector_type(4))) int   i32x4;

// raw waitcnt: vmcnt(n) with lgkmcnt/expcnt unconstrained (gfx9 encoding)
#define WAITVM(n) __builtin_amdgcn_s_waitcnt(0xF70 | (n))
#define BARRIER() __builtin_amdgcn_s_barrier()

// ---------- helpers ----------
__device__ __forceinline__ void async16(const void* g, void* l) {
    __builtin_amdgcn_global_load_lds(
        (const __attribute__((address_space(1))) unsigned int*)g,
        (__attribute__((address_space(3))) unsigned int*)l,
        16, 0, 0);
}

// ---------- kernel 1: L2-normalize rows -> i8 reps (scale 127), fp32 positives ----------
__global__ __launch_bounds__(256) void norm_pos_kernel(
    const float* __restrict__ emb_i, const float* __restrict__ emb_j,
    unsigned char* __restrict__ reps, float* __restrict__ pos,
    float* __restrict__ out)
{
    __shared__ float sc[3][4];
    int b = blockIdx.x, t = threadIdx.x;
    if (b == 0 && t == 0) out[0] = 0.0f;       // loss kernel accumulates atomically

    const float2* ri = (const float2*)(emb_i + (size_t)b * DIM);
    const float2* rj = (const float2*)(emb_j + (size_t)b * DIM);
    float2 xi = ri[t], xj = rj[t];
    float si = xi.x * xi.x + xi.y * xi.y;
    float sj = xj.x * xj.x + xj.y * xj.y;
    #pragma unroll
    for (int o = 32; o > 0; o >>= 1) { si += __shfl_down(si, o, 64); sj += __shfl_down(sj, o, 64); }
    int lane = t & 63, w = t >> 6;
    if (lane == 0) { sc[0][w] = si; sc[1][w] = sj; }
    __syncthreads();
    float ni2 = sc[0][0] + sc[0][1] + sc[0][2] + sc[0][3];
    float nj2 = sc[1][0] + sc[1][1] + sc[1][2] + sc[1][3];
    float rni = 1.0f / fmaxf(sqrtf(ni2), 1e-12f);
    float rnj = 1.0f / fmaxf(sqrtf(nj2), 1e-12f);
    float zix = xi.x * rni, ziy = xi.y * rni;
    float zjx = xj.x * rnj, zjy = xj.y * rnj;
    // symmetric i8 quant, scale 127 (|z| <= 1 -> |q| <= 127, exact i32 dot later)
    int qix = __float2int_rn(zix * 127.0f), qiy = __float2int_rn(ziy * 127.0f);
    int qjx = __float2int_rn(zjx * 127.0f), qjy = __float2int_rn(zjy * 127.0f);
    ((unsigned short*)(reps + (size_t)b * DIM))[t] =
        (unsigned short)((qix & 0xFF) | ((qiy & 0xFF) << 8));
    ((unsigned short*)(reps + (size_t)(b + B_SIZE) * DIM))[t] =
        (unsigned short)((qjx & 0xFF) | ((qjy & 0xFF) << 8));
    float d = zix * zjx + ziy * zjy;
    #pragma unroll
    for (int o = 32; o > 0; o >>= 1) d += __shfl_down(d, o, 64);
    if (lane == 0) sc[2][w] = d;
    __syncthreads();
    if (t == 0) pos[b] = sc[2][0] + sc[2][1] + sc[2][2] + sc[2][3];
}

// ---------- kernel 2: symmetric fused R*R^T (i8 MFMA, 2x fp8 rate) + masked exp sums ----------
// ROUND 10: mfma_i32_16x16x64_i8 (K=64/instruction, ~2x the fp8-e4m3 rate). Per wave per
// K-tile: 16 MFMAs + 8 ds_read_b128 (one swizzled 16-B piece per fragment: lane (lm,quad)
// needs k = quad*16..quad*16+15 = piece quad ^ swz -> 64 lanes cover 64 distinct chunks,
// conflict-free). acc = i32x4[4][4] = 64 AGPR (exact integer dot, sim = acc/127^2).
// C/D layout shape-determined (dtype-independent, verified): col=lane&15, row=quad*4+reg
// -> epilogue identical to r9's verified LDS-transpose reduction.
// Skeleton byte-identical to r9: 256x128 tile, 8 waves of 64x64, launch_bounds(512,4)
// -> 2 blocks/CU; 2-buffer/2-barrier, counted vmcnt(3); atomic-free part[64][8192].
#define BK 64
#define KITERS 8             // DIM / BK
#define RSTR 20              // red row stride in words (80 B: 16-aligned, bank-spread)

__global__ __launch_bounds__(512, 4) void sim_denom_kernel(
    const unsigned char* __restrict__ reps,
    const int* __restrict__ target,
    float* __restrict__ part)
{
    // unified LDS: staging layout [As0 16K | As1 16K | Bs0 8K | Bs1 8K] = 48 KB;
    // epilogue overlay [red0 20K | red1 20K | red_col 2K] (fenced by k=7 barrier)
    __shared__ __align__(16) unsigned char SMEM[49152];
    unsigned char* As0 = SMEM;
    unsigned char* As1 = SMEM + 16384;
    unsigned char* Bs0 = SMEM + 32768;
    unsigned char* Bs1 = SMEM + 40960;

    int t = threadIdx.x;
    // XCD-chunked remap: contiguous 132-run per XCD (1056 = 8*132, bijective).
    int id0 = blockIdx.x;
    int id = (id0 & 7) * 132 + (id0 >> 3);

    // --- band decode: 8x16 (I,J) supertile bands over the J>=2I region ---
    const int bA[10]   = {0,0,0,0,1,1,1,2,2,3};
    const int bB[10]   = {0,1,2,3,1,2,3,2,3,3};
    const int boff[11] = {0,72,200,328,456,528,656,784,856,984,1056};
    int s = 0;
    while (boff[s + 1] <= id) s++;
    int l = id - boff[s];
    int I, J;
    if (bA[s] == bB[s]) {                 // triangular band: start(r) = r*(17-r)
        int r = 0;
        while ((r + 1) * (16 - r) <= l) r++;
        I = bA[s] * 8 + r;
        J = bB[s] * 16 + 2 * r + (l - r * (17 - r));
    } else { I = bA[s] * 8 + (l >> 4); J = bB[s] * 16 + (l & 15); }

    int brow = I * 256;
    int bcol = J * 128;

    int wave = t >> 6, lane = t & 63;
    int wr = wave >> 1, wc = wave & 1;       // 4x2 waves, each 64x64 output
    int quad = lane >> 4, lm = lane & 15;

    i32x4 acc[4][4];
    #pragma unroll
    for (int i = 0; i < 4; i++)
        #pragma unroll
        for (int j = 0; j < 4; j++) acc[i][j] = (i32x4)0;

    // staging: A: 2 calls, call c -> row c*128 + (t>>2), LDS byte t*16 + c*8192;
    // B: 1 call, row t>>2. swizzled source piece = (t&3) ^ ((row ^ (row>>2)) & 3)
    int srow = t >> 2;
    int sp   = (t & 3) ^ ((srow ^ (srow >> 2)) & 3);
    const unsigned char* gA = reps + (size_t)(brow + srow) * DIM + sp * 16;
    const unsigned char* gB = reps + (size_t)(bcol + srow) * DIM + sp * 16;

    auto stage = [&](unsigned char* Ab, unsigned char* Bb, int k0) {
        async16(gA + k0, Ab + t * 16);
        async16(gA + k0 + 128 * DIM, Ab + t * 16 + 8192);
        async16(gB + k0, Bb + t * 16);
    };
    auto compute = [&](const unsigned char* Ab, const unsigned char* Bb) {
        i32x4 bf[4];
        #pragma unroll
        for (int ni = 0; ni < 4; ni++) {
            int cl = wc * 64 + ni * 16 + lm;               // 0..127
            int p = quad ^ ((cl ^ (cl >> 2)) & 3);
            bf[ni] = *(const i32x4*)(Bb + cl * 64 + p * 16);
        }
        #pragma unroll
        for (int mi = 0; mi < 4; mi++) {
            int rl = wr * 64 + mi * 16 + lm;               // 0..255
            int p = quad ^ ((rl ^ (rl >> 2)) & 3);
            i32x4 af = *(const i32x4*)(Ab + rl * 64 + p * 16);
            #pragma unroll
            for (int ni = 0; ni < 4; ni++)
                acc[mi][ni] = __builtin_amdgcn_mfma_i32_16x16x64_i8(
                    af, bf[ni], acc[mi][ni], 0, 0, 0);
        }
    };

    // prologue: two tiles in flight (6 DMAs outstanding per thread)
    stage(As0, Bs0, 0);
    stage(As1, Bs1, BK);

    #pragma unroll
    for (int k = 0; k < KITERS; k++) {
        unsigned char* Ac = (k & 1) ? As1 : As0;
        unsigned char* Bc = (k & 1) ? Bs1 : Bs0;
        if (k < KITERS - 1) WAITVM(3); else WAITVM(0);   // drain loads(k), keep loads(k+1) in flight
        BARRIER();                         // all waves' loads(k) landed
        compute(Ac, Bc);
        BARRIER();                         // all waves done reading buf(k)
        if (k + 2 < KITERS) stage(Ac, Bc, (k + 2) * BK);
    }

    // ---------- epilogue: masked exp + row/col sums, atomic-free, shfl-free rows ----------
    // C/D layout: col=lane&15, row=quad*4+reg. Wave's rows all in one 128-half h.
    // Positives: global col-row = 4096 <=> (J - rtile)==32 at ((rl&127)==cl).
    int h = wr >> 1;
    int rtile = 2 * I + h;
    bool haspos = (J - rtile == 32);
    int labc[4];
    #pragma unroll
    for (int ni = 0; ni < 4; ni++)
        labc[ni] = target[(bcol + wc * 64 + ni * 16 + lm) & (B_SIZE - 1)];

    float* red0    = (float*)SMEM;               // [256][RSTR] lm-partials, wc=0
    float* red1    = (float*)(SMEM + 20480);     // [256][RSTR] lm-partials, wc=1
    float* red_col = (float*)(SMEM + 40960);     // [2][2][128] col partials
    float* redw    = wc ? red1 : red0;

    float colacc[4] = {0.f, 0.f, 0.f, 0.f};
    #pragma unroll
    for (int mi = 0; mi < 4; mi++) {
        #pragma unroll
        for (int r = 0; r < 4; r++) {
            int rl = wr * 64 + mi * 16 + quad * 4 + r;     // 0..255
            int labr = target[(brow + rl) & (B_SIZE - 1)];
            float rowacc = 0.0f;
            #pragma unroll
            for (int ni = 0; ni < 4; ni++) {
                int cl = wc * 64 + ni * 16 + lm;
                bool pospair = haspos && ((rl & 127) == cl);
                bool masked = (labr == labc[ni]) && !pospair;
                float e = masked ? 0.0f
                                 : __builtin_amdgcn_exp2f(
                                       (float)acc[mi][ni][r] * IEXP_SCALE);
                rowacc += e;
                colacc[ni] += e;
            }
            redw[rl * RSTR + lm] = rowacc;       // all 64 lanes, distinct (rl,lm) slots
        }
    }
    #pragma unroll
    for (int ni = 0; ni < 4; ni++) {
        float c = colacc[ni];
        c += __shfl_xor(c, 16, 64);
        c += __shfl_xor(c, 32, 64);
        if (quad == 0) red_col[h * 256 + (wr & 1) * 128 + wc * 64 + ni * 16 + lm] = c;
    }
    BARRIER();
    if (t < 256) {
        int th = t >> 7;                       // row-half of this output row
        if (2 * I + th <= J) {                 // suppress even-diag duplicate lower half
            const f32x4* r0 = (const f32x4*)(red0 + t * RSTR);
            const f32x4* r1 = (const f32x4*)(red1 + t * RSTR);
            f32x4 v = r0[0] + r0[1] + r0[2] + r0[3]
                    + r1[0] + r1[1] + r1[2] + r1[3];
            part[(size_t)J * TWO_B + brow + t] = v[0] + v[1] + v[2] + v[3];
        }
    } else if (t < 512) {
        int c = t - 256;
        int ch = c >> 7, cc = c & 127;         // which row-half's col-sums
        int rt = 2 * I + ch;
        if (rt < J) {                          // skip diag (row-side covers) + duplicate half
            float cs = red_col[ch * 256 + cc] + red_col[ch * 256 + 128 + cc];
            part[(size_t)rt * TWO_B + bcol + cc] = cs;
        }
    }
}

// ---------- kernel 3: final loss (sum 64 part slices, then log/pos reduce) ----------
__global__ __launch_bounds__(256) void loss_kernel(
    const float* __restrict__ part, const float* __restrict__ pos,
    float* __restrict__ out)
{
    __shared__ float sc[4];
    int t = threadIdx.x, b = blockIdx.x;
    int i = b * 256 + t;
    float s = 0.0f;
    #pragma unroll
    for (int x = 0; x < 64; x++) s += part[(size_t)x * TWO_B + i];
    float v = logf(s + 1e-7f);                         // 32 blocks x 256 = 8192
    float p = (i < B_SIZE) ? pos[i] : 0.0f;
    // loss = (sum log(denom) - (2/t) * sum pos) / 2B ; 2/t = 4
    float v2 = v - 4.0f * p;
    #pragma unroll
    for (int o = 32; o > 0; o >>= 1) v2 += __shfl_down(v2, o, 64);
    int lane = t & 63, w = t >> 6;
    if (lane == 0) sc[w] = v2;
    __syncthreads();
    if (t == 0) atomicAdd(out, (sc[0] + sc[1] + sc[2] + sc[3]) * (1.0f / (float)TWO_B));
}

// ---------- launcher ----------
extern "C" void kernel_launch(void* const* d_in, const int* in_sizes, int n_in,
                              void* d_out, int out_size, void* d_ws, size_t ws_size,
                              hipStream_t stream)
{
    const float* emb_i  = (const float*)d_in[0];
    const float* emb_j  = (const float*)d_in[1];
    const int*   target = (const int*)d_in[2];
    float* out = (float*)d_out;

    char* ws = (char*)d_ws;
    unsigned char* reps = (unsigned char*)ws;                        // 8192*512 = 4 MB (i8)
    float* pos   = (float*)(ws + (size_t)TWO_B * DIM);               // 16 KB
    float* part  = (float*)(ws + (size_t)TWO_B * DIM + B_SIZE * 4);  // 64*8192*4 = 2 MB

    norm_pos_kernel<<<B_SIZE, 256, 0, stream>>>(emb_i, emb_j, reps, pos, out);
    sim_denom_kernel<<<NBLK, 512, 0, stream>>>(reps, target, part);
    loss_kernel<<<TWO_B / 256, 256, 0, stream>>>(part, pos, out);
}